// Round 5
// baseline (1270.332 us; speedup 1.0000x reference)
//
#include <hip/hip_runtime.h>

#define BSZ   2
#define LSEQ  2048
#define DQ    512
#define SQ    4
#define EPSQ  1e-6f

typedef float nfloat4 __attribute__((ext_vector_type(4)));  // native vec for nontemporal
typedef float nfloat2 __attribute__((ext_vector_type(2)));  // VOP3P packed pair

__device__ __forceinline__ nfloat2 mk2(float x, float y) { nfloat2 v; v.x = x; v.y = y; return v; }

// ---------------- packed quaternion (pairs (r,i),(j,k); v_pk_fma_f32 path) ---
struct PQuat { nfloat2 ri, jk; };

__device__ __forceinline__ PQuat pq_of(const float4 v) {
    PQuat p; p.ri = mk2(v.x, v.y); p.jk = mk2(v.z, v.w); return p;
}
__device__ __forceinline__ float4 f4_of(const PQuat p) {
    return make_float4(p.ri.x, p.ri.y, p.jk.x, p.jk.y);
}

// o = a x b  (8 packed mul/fma vs 16 scalar)
__device__ __forceinline__ PQuat pqmul(const PQuat a, const PQuat b) {
    const float ar = a.ri.x, ai = a.ri.y, aj = a.jk.x, ak = a.jk.y;
    PQuat o;
    o.ri = ar*b.ri + ai*mk2(-b.ri.y,  b.ri.x)
         + aj*mk2(-b.jk.x,  b.jk.y) + ak*mk2(-b.jk.y, -b.jk.x);
    o.jk = ar*b.jk + ai*mk2(-b.jk.y,  b.jk.x)
         + aj*mk2( b.ri.x, -b.ri.y) + ak*mk2( b.ri.y,  b.ri.x);
    return o;
}

// o = a x b + c
__device__ __forceinline__ PQuat pqmuladd(const PQuat a, const PQuat b, const PQuat c) {
    const float ar = a.ri.x, ai = a.ri.y, aj = a.jk.x, ak = a.jk.y;
    PQuat o;
    o.ri = c.ri + ar*b.ri + ai*mk2(-b.ri.y,  b.ri.x)
         + aj*mk2(-b.jk.x,  b.jk.y) + ak*mk2(-b.jk.y, -b.jk.x);
    o.jk = c.jk + ar*b.jk + ai*mk2(-b.jk.y,  b.jk.x)
         + aj*mk2( b.ri.x, -b.ri.y) + ak*mk2( b.ri.y,  b.ri.x);
    return o;
}

// Precomputed per-(d,s) A-quaternion state (hA = 0.5*dt-free part).
struct HA { float r, i; nfloat2 jk; float p2, n2r; };

__device__ __forceinline__ HA load_hA(const float* __restrict__ Alog,
                                      const float* __restrict__ Ai,
                                      const float* __restrict__ Aj,
                                      const float* __restrict__ Ak, int idx) {
    HA h;
    h.r  = -0.5f * __expf(Alog[idx]);
    h.i  =  0.5f * Ai[idx];
    h.jk = mk2(0.5f * Aj[idx], 0.5f * Ak[idx]);
    h.p2 = h.r*h.r + h.i*h.i + h.jk.x*h.jk.x + h.jk.y*h.jk.y;
    h.n2r = -2.0f * h.r;
    return h;
}

// Cayley transition q and injection Bu (packed, strength-reduced).
__device__ __forceinline__ void cayley_pk(const float a, const float aa, const HA& hA,
                                          const PQuat B, const PQuat U,
                                          PQuat& q, PQuat& Bu) {
    const float dd = __builtin_fmaf(aa, hA.p2, __builtin_fmaf(a, hA.n2r, 1.0f + EPSQ));
    const float sv = __builtin_amdgcn_rcpf(dd);
    const float nr = __builtin_fmaf(-aa, hA.p2, 1.0f);   // 1 - |w|^2
    const float as = a * sv;
    const float s2a = as + as;                            // 2*a*s
    q.ri = mk2(nr * sv, s2a * hA.i);
    q.jk = s2a * hA.jk;
    PQuat cd;                                             // conj(den) = (1-wr, w_im)
    cd.ri = mk2(__builtin_fmaf(-a, hA.r, 1.0f), a * hA.i);
    cd.jk = a * hA.jk;
    const PQuat cb = pqmul(cd, B);
    PQuat dB; dB.ri = as * cb.ri; dB.jk = as * cb.jk;
    Bu = pqmul(dB, U);
}

// ---------------- scalar quat (fallback pass2 only) --------------------------
struct Quat { float r, i, j, k; };
__device__ __forceinline__ Quat qmul(const Quat a, const Quat b) {
    Quat o;
    o.r = a.r*b.r - a.i*b.i - a.j*b.j - a.k*b.k;
    o.i = a.r*b.i + a.i*b.r + a.j*b.k - a.k*b.j;
    o.j = a.r*b.j - a.i*b.k + a.j*b.r + a.k*b.i;
    o.k = a.r*b.k + a.i*b.j - a.j*b.i + a.k*b.r;
    return o;
}
__device__ __forceinline__ Quat qmuladd(const Quat a, const Quat b, const Quat c) {
    Quat o;
    o.r = c.r + a.r*b.r - a.i*b.i - a.j*b.j - a.k*b.k;
    o.i = c.i + a.r*b.i + a.i*b.r + a.j*b.k - a.k*b.j;
    o.j = c.j + a.r*b.j - a.i*b.k + a.j*b.r + a.k*b.i;
    o.k = c.k + a.r*b.k + a.i*b.j - a.j*b.i + a.k*b.r;
    return o;
}
__device__ __forceinline__ Quat q_of(const float4 v) { return Quat{v.x, v.y, v.z, v.w}; }
__device__ __forceinline__ float4 f4s_of(const Quat q) { return make_float4(q.r, q.i, q.j, q.k); }

// ---------------- async global->LDS staging helpers --------------------------
typedef unsigned int u32_t;
__device__ __forceinline__ void gl_lds16(const void* g, void* l) {
    __builtin_amdgcn_global_load_lds(
        (const __attribute__((address_space(1))) u32_t*)g,
        (__attribute__((address_space(3))) u32_t*)l, 16, 0, 0);
}
__device__ __forceinline__ void gl_lds4(const void* g, void* l) {
    __builtin_amdgcn_global_load_lds(
        (const __attribute__((address_space(1))) u32_t*)g,
        (__attribute__((address_space(3))) u32_t*)l, 4, 0, 0);
}

// ======================= single-kernel decoupled look-back ===================
// Chains: (b, dblk) = 8; chunks per chain NCHL=128 (CH=16 steps). Block =
// 512 thr (128 d x 4 s), 42 KB LDS -> 3 blocks/CU. Ticket-ordered chunk
// assignment makes the look-back deadlock-free regardless of dispatch order
// (predecessor chunks hold lower tickets => resident-or-done). Publication
// via AGENT-scope release/acquire atomics (cross-XCD-safe). Chunk data staged
// once in LDS serves BOTH summary and replay.
#define NCHL   128
#define CHL    (LSEQ / NCHL)          // 16
#define NCHAIN (BSZ * (DQ / 128))     // 8

__global__ __launch_bounds__(512, 6) void qssm_lookback(
    const float* __restrict__ u, const float* __restrict__ dt,
    const float* __restrict__ Bin, const float* __restrict__ Cin,
    const float* __restrict__ Alog, const float* __restrict__ Ai,
    const float* __restrict__ Aj,   const float* __restrict__ Ak,
    int* __restrict__ flags, int* __restrict__ ticket,
    float4* __restrict__ WQ, float4* __restrict__ WB, float4* __restrict__ WH,
    float* __restrict__ out)
{
    __shared__ float4 uL[CHL][128];
    __shared__ float  dtL[CHL][128];
    __shared__ float4 BL[CHL][SQ];
    __shared__ float4 CL[CHL][SQ];
    __shared__ int sbid;

    const int t    = threadIdx.x;
    const int lane = t & 63;
    const int wid  = t >> 6;

    if (t == 0) sbid = atomicAdd(ticket, 1);
    __syncthreads();
    const int bid   = sbid;
    const int chain = bid & (NCHAIN - 1);
    const int c     = bid >> 3;           // chunk index 0..NCHL-1
    const int b     = chain >> 2;
    const int dblk  = chain & 3;
    const int t0    = c * CHL;
    const int base  = b * LSEQ + t0;

    // ---- stage chunk (u 32K, dt 8K, B 1K, C 1K) ----
    const float4* ug  = (const float4*)u + (size_t)base*DQ + dblk*128;
    const float*  dtg = dt + (size_t)base*DQ + dblk*128;
    const float*  Bg  = Bin + (size_t)base*SQ*4;
    const float*  Cg  = Cin + (size_t)base*SQ*4;
#pragma unroll
    for (int jj = 0; jj < CHL/8; ++jj) {          // 8 waves x 2 rows
        const int j = wid*(CHL/8) + jj;
#pragma unroll
        for (int k = 0; k < 2; ++k) {
            gl_lds16(ug  + (size_t)j*DQ + k*64 + lane, &uL[j][k*64]);
            gl_lds4 (dtg + (size_t)j*DQ + k*64 + lane, &dtL[j][k*64]);
        }
    }
    if (wid == 0) {
#pragma unroll
        for (int k = 0; k < (CHL*SQ*4)/64; ++k)
            gl_lds4(Bg + k*64 + lane, ((float*)BL) + k*64);
    } else if (wid == 1) {
#pragma unroll
        for (int k = 0; k < (CHL*SQ*4)/64; ++k)
            gl_lds4(Cg + k*64 + lane, ((float*)CL) + k*64);
    }

    const int dl   = lane & 15;
    const int sq   = lane >> 4;           // s-channel 0..3
    const int dloc = wid*16 + dl;         // 0..127
    const int d    = dblk*128 + dloc;

    const HA hA = load_hA(Alog, Ai, Aj, Ak, d*SQ + sq);
    const size_t rowbase = ((size_t)(b*SQ + sq)*NCHL)*DQ + d;   // + c*DQ per chunk
    const size_t myidx   = rowbase + (size_t)c*DQ;

    __syncthreads();                      // drains vmcnt (global_load_lds)

    // ---- local summary (Q, Bc) over CHL steps ----
    PQuat Q, Bc;
    {
        const float a  = dtL[0][dloc];
        cayley_pk(a, a*a, hA, pq_of(BL[0][sq]), pq_of(uL[0][dloc]), Q, Bc);
    }
#pragma unroll
    for (int j = 1; j < CHL; ++j) {
        const float a  = dtL[j][dloc];
        PQuat q, Bu;
        cayley_pk(a, a*a, hA, pq_of(BL[j][sq]), pq_of(uL[j][dloc]), q, Bu);
        Bc = pqmuladd(q, Bc, Bu);
        Q  = pqmul(q, Q);
    }
    WQ[myidx] = f4_of(Q);
    WB[myidx] = f4_of(Bc);
    __syncthreads();                      // all waves' stores drained (vmcnt0 at barrier)
    if (c > 0 && t == 0)
        __hip_atomic_store(&flags[chain*NCHL + c], 1, __ATOMIC_RELEASE, __HIP_MEMORY_SCOPE_AGENT);

    // ---- look-back: exclusive prefix hx ----
    PQuat hx;
    if (c == 0) {
        hx.ri = mk2(0.f, 0.f); hx.jk = mk2(0.f, 0.f);
        WH[myidx] = f4_of(Bc);            // inclusive through chunk 0 = Bc
        __syncthreads();
        if (t == 0)
            __hip_atomic_store(&flags[chain*NCHL], 2, __ATOMIC_RELEASE, __HIP_MEMORY_SCOPE_AGENT);
    } else {
        PQuat QF; QF.ri = mk2(1.f, 0.f); QF.jk = mk2(0.f, 0.f);   // identity
        PQuat BF; BF.ri = mk2(0.f, 0.f); BF.jk = mk2(0.f, 0.f);
        int j = c - 1;
        bool done = false;
        while (!done) {
            // every thread acquire-loads the flags it needs (same addr -> broadcast)
            const int m = (j + 1 < 4) ? (j + 1) : 4;
            int f[4] = {0, 0, 0, 0};
#pragma unroll
            for (int k = 0; k < 4; ++k)
                if (k < m)
                    f[k] = __hip_atomic_load(&flags[chain*NCHL + j - k],
                                             __ATOMIC_ACQUIRE, __HIP_MEMORY_SCOPE_AGENT);
            int cons = 0, term = -1;
            if (f[0] == 2) term = 0;
            else if (f[0] == 1) { cons = 1;
                if (f[1] == 2) term = 1;
                else if (f[1] == 1) { cons = 2;
                    if (f[2] == 2) term = 2;
                    else if (f[2] == 1) { cons = 3;
                        if (f[3] == 2) term = 3;
                        else if (f[3] == 1) cons = 4; } } }
            if (cons == 0 && term < 0) { __builtin_amdgcn_s_sleep(2); continue; }
            // batch-load data (independent loads overlap)
            float4 qv[4], bv[4], hterm;
#pragma unroll
            for (int k = 0; k < 4; ++k)
                if (k < cons) { qv[k] = WQ[rowbase + (size_t)(j - k)*DQ];
                                bv[k] = WB[rowbase + (size_t)(j - k)*DQ]; }
            if (term >= 0) hterm = WH[rowbase + (size_t)(j - term)*DQ];
            // compose partials (later-first walk: F <- F o T_j)
#pragma unroll
            for (int k = 0; k < 4; ++k)
                if (k < cons) {
                    const PQuat Qj = pq_of(qv[k]);
                    const PQuat Bj = pq_of(bv[k]);
                    BF = pqmuladd(QF, Bj, BF);   // BF' = QF*Bj + BF
                    QF = pqmul(QF, Qj);          // QF' = QF*Qj
                }
            if (term >= 0) { hx = pqmuladd(QF, pq_of(hterm), BF); done = true; }
            else j -= cons;
        }
        // publish inclusive h_c = Q*hx + Bc
        const PQuat hinc = pqmuladd(Q, hx, Bc);
        WH[myidx] = f4_of(hinc);
        __syncthreads();
        if (t == 0)
            __hip_atomic_store(&flags[chain*NCHL + c], 2, __ATOMIC_RELEASE, __HIP_MEMORY_SCOPE_AGENT);
    }

    // ---- replay from hx, emit y (LDS chunk data still resident) ----
    PQuat h = hx;
    nfloat4* outp = (nfloat4*)out + (size_t)base*DQ + d;
#pragma unroll
    for (int j = 0; j < CHL; ++j) {
        const float a = dtL[j][dloc];
        PQuat q, Bu;
        cayley_pk(a, a*a, hA, pq_of(BL[j][sq]), pq_of(uL[j][dloc]), q, Bu);
        h = pqmuladd(q, h, Bu);
        const PQuat y = pqmul(pq_of(CL[j][sq]), h);
        float yr = y.ri.x, yi = y.ri.y, yj = y.jk.x, yk = y.jk.y;
        yr += __shfl_xor(yr, 16); yi += __shfl_xor(yi, 16);
        yj += __shfl_xor(yj, 16); yk += __shfl_xor(yk, 16);
        yr += __shfl_xor(yr, 32); yi += __shfl_xor(yi, 32);
        yj += __shfl_xor(yj, 32); yk += __shfl_xor(yk, 32);
        if (sq == 0) {
            const nfloat4 yv = {yr, yi, yj, yk};
            __builtin_nontemporal_store(yv, outp);   // out never re-read
        }
        outp += DQ;
    }
}

// ======================= fallback 3-kernel path (r2, proven 151.7) ===========
template<int NCH>
__global__ __launch_bounds__(256, 6) void qssm_pass1(
    const float* __restrict__ u, const float* __restrict__ dt,
    const float* __restrict__ Bin,
    const float* __restrict__ Alog, const float* __restrict__ Ai,
    const float* __restrict__ Aj,   const float* __restrict__ Ak,
    float4* __restrict__ WQ, float4* __restrict__ WB)
{
    constexpr int CH = LSEQ / NCH;
    __shared__ float4 uL[CH][128];
    __shared__ float  dtL[CH][128];
    __shared__ float4 BL[CH][SQ];

    const int t    = threadIdx.x;
    const int lane = t & 63;
    const int wid  = t >> 6;
    const int dblk = blockIdx.x;
    const int c    = blockIdx.y;
    const int b    = blockIdx.z;
    const int t0   = c * CH;
    const int base = b*LSEQ + t0;

    const float4* ug  = (const float4*)u + (size_t)base*DQ + dblk*128;
    const float*  dtg = dt + (size_t)base*DQ + dblk*128;
    const float*  Bg  = Bin + (size_t)base*SQ*4;
#pragma unroll
    for (int jj = 0; jj < CH/4; ++jj) {
        const int j = wid*(CH/4) + jj;
#pragma unroll
        for (int k = 0; k < 2; ++k) {
            gl_lds16(ug  + (size_t)j*DQ + k*64 + lane, &uL[j][k*64]);
            gl_lds4 (dtg + (size_t)j*DQ + k*64 + lane, &dtL[j][k*64]);
        }
    }
    if (wid == 0) {
#pragma unroll
        for (int k = 0; k < 2; ++k)
            gl_lds4(Bg + k*64 + lane, ((float*)BL) + k*64);
    }

    const int dl = t & 127;
    const int sh = t >> 7;
    const int s0 = sh * 2;
    const int d  = dblk*128 + dl;

    HA hA0 = load_hA(Alog, Ai, Aj, Ak, d*SQ + s0);
    HA hA1 = load_hA(Alog, Ai, Aj, Ak, d*SQ + s0 + 1);

    __syncthreads();

    PQuat Q[2], Bc[2];
    {
        const float a  = dtL[0][dl];
        const float aa = a * a;
        const PQuat U  = pq_of(uL[0][dl]);
        PQuat q, Bu;
        cayley_pk(a, aa, hA0, pq_of(BL[0][s0]),     U, q, Bu);
        Q[0] = q; Bc[0] = Bu;
        cayley_pk(a, aa, hA1, pq_of(BL[0][s0 + 1]), U, q, Bu);
        Q[1] = q; Bc[1] = Bu;
    }
#pragma unroll
    for (int j = 1; j < CH; ++j) {
        const float a  = dtL[j][dl];
        const float aa = a * a;
        const PQuat U  = pq_of(uL[j][dl]);
        PQuat q, Bu;
        cayley_pk(a, aa, hA0, pq_of(BL[j][s0]),     U, q, Bu);
        Bc[0] = pqmuladd(q, Bc[0], Bu);
        Q[0]  = pqmul(q, Q[0]);
        cayley_pk(a, aa, hA1, pq_of(BL[j][s0 + 1]), U, q, Bu);
        Bc[1] = pqmuladd(q, Bc[1], Bu);
        Q[1]  = pqmul(q, Q[1]);
    }
#pragma unroll
    for (int ss = 0; ss < 2; ++ss) {
        const size_t idx = ((size_t)(b*SQ + s0 + ss)*NCH + c)*DQ + d;
        WQ[idx] = f4_of(Q[ss]);
        WB[idx] = f4_of(Bc[ss]);
    }
}

template<int NCH>
__global__ __launch_bounds__(512) void qssm_pass2(
    const float4* __restrict__ WQ, float4* __restrict__ WB)
{
    constexpr int GS = 8;
    constexpr int NG = NCH / GS;
    __shared__ float4 QL[NG][16];
    __shared__ float4 BL2[NG][16];
    __shared__ float4 HS[NG][16];

    const int t  = threadIdx.x;
    const int i  = t & 15;
    const int g  = t >> 4;
    const int bs = blockIdx.x >> 5;
    const int d  = (blockIdx.x & 31) * 16 + i;
    const size_t chbase = (size_t)bs * NCH * DQ + d;

    size_t idx = chbase + (size_t)(g * GS) * DQ;
    Quat Qa = q_of(WQ[idx]);
    Quat Ba = q_of(WB[idx]);
#pragma unroll
    for (int j = 1; j < GS; ++j) {
        idx += DQ;
        const Quat Qc = q_of(WQ[idx]);
        const Quat Bc = q_of(WB[idx]);
        Ba = qmuladd(Qc, Ba, Bc);
        Qa = qmul(Qc, Qa);
    }
    QL[g][i]  = f4s_of(Qa);
    BL2[g][i] = f4s_of(Ba);
    __syncthreads();

    if (t < 16) {
        Quat h{0.f, 0.f, 0.f, 0.f};
#pragma unroll
        for (int gg = 0; gg < NG; ++gg) {
            HS[gg][t] = f4s_of(h);
            h = qmuladd(q_of(QL[gg][t]), h, q_of(BL2[gg][t]));
        }
    }
    __syncthreads();

    Quat h = q_of(HS[g][i]);
    idx = chbase + (size_t)(g * GS) * DQ;
#pragma unroll
    for (int j = 0; j < GS; ++j) {
        const Quat Qc = q_of(WQ[idx]);
        const Quat Bc = q_of(WB[idx]);
        WB[idx] = f4s_of(h);
        h = qmuladd(Qc, h, Bc);
        idx += DQ;
    }
}

template<int NCH>
__global__ __launch_bounds__(256, 6) void qssm_pass3(
    const float* __restrict__ u, const float* __restrict__ dt,
    const float* __restrict__ Bin, const float* __restrict__ Cin,
    const float* __restrict__ Alog, const float* __restrict__ Ai,
    const float* __restrict__ Aj,   const float* __restrict__ Ak,
    const float4* __restrict__ WB, float* __restrict__ out)
{
    constexpr int CH = LSEQ / NCH;
    __shared__ float4 uL[CH][128];
    __shared__ float  dtL[CH][128];
    __shared__ float4 BL[CH][SQ];
    __shared__ float4 CL[CH][SQ];

    const int t    = threadIdx.x;
    const int lane = t & 63;
    const int wid  = t >> 6;
    const int dblk = blockIdx.x;
    const int c    = blockIdx.y;
    const int b    = blockIdx.z;
    const int t0   = c * CH;
    const int base = b*LSEQ + t0;

    const float4* ug  = (const float4*)u + (size_t)base*DQ + dblk*128;
    const float*  dtg = dt + (size_t)base*DQ + dblk*128;
    const float*  Bg  = Bin + (size_t)base*SQ*4;
    const float*  Cg  = Cin + (size_t)base*SQ*4;
#pragma unroll
    for (int jj = 0; jj < CH/4; ++jj) {
        const int j = wid*(CH/4) + jj;
#pragma unroll
        for (int k = 0; k < 2; ++k) {
            gl_lds16(ug  + (size_t)j*DQ + k*64 + lane, &uL[j][k*64]);
            gl_lds4 (dtg + (size_t)j*DQ + k*64 + lane, &dtL[j][k*64]);
        }
    }
    if (wid == 0) {
#pragma unroll
        for (int k = 0; k < 2; ++k)
            gl_lds4(Bg + k*64 + lane, ((float*)BL) + k*64);
    } else if (wid == 1) {
#pragma unroll
        for (int k = 0; k < 2; ++k)
            gl_lds4(Cg + k*64 + lane, ((float*)CL) + k*64);
    }

    const int dl   = lane & 31;
    const int sh   = lane >> 5;
    const int s0   = sh * 2;
    const int dloc = wid*32 + dl;
    const int d    = dblk*128 + dloc;

    HA hA0 = load_hA(Alog, Ai, Aj, Ak, d*SQ + s0);
    HA hA1 = load_hA(Alog, Ai, Aj, Ak, d*SQ + s0 + 1);
    PQuat h0 = pq_of(WB[((size_t)(b*SQ + s0    )*NCH + c)*DQ + d]);
    PQuat h1 = pq_of(WB[((size_t)(b*SQ + s0 + 1)*NCH + c)*DQ + d]);

    nfloat4* outp = (nfloat4*)out + (size_t)base*DQ + d;

    __syncthreads();

#pragma unroll
    for (int j = 0; j < CH; ++j) {
        const float a  = dtL[j][dloc];
        const float aa = a * a;
        const PQuat U  = pq_of(uL[j][dloc]);
        PQuat y; y.ri = mk2(0.f, 0.f); y.jk = mk2(0.f, 0.f);
        PQuat q, Bu;
        cayley_pk(a, aa, hA0, pq_of(BL[j][s0]),     U, q, Bu);
        h0 = pqmuladd(q, h0, Bu);
        y  = pqmuladd(pq_of(CL[j][s0]),     h0, y);
        cayley_pk(a, aa, hA1, pq_of(BL[j][s0 + 1]), U, q, Bu);
        h1 = pqmuladd(q, h1, Bu);
        y  = pqmuladd(pq_of(CL[j][s0 + 1]), h1, y);
        float yr = y.ri.x + __shfl_xor(y.ri.x, 32);
        float yi = y.ri.y + __shfl_xor(y.ri.y, 32);
        float yj = y.jk.x + __shfl_xor(y.jk.x, 32);
        float yk = y.jk.y + __shfl_xor(y.jk.y, 32);
        if (sh == 0) {
            const nfloat4 yv = {yr, yi, yj, yk};
            __builtin_nontemporal_store(yv, outp);
        }
        outp += DQ;
    }
}

// ======================= host launch =========================================
template<int NCH>
static void launch_all(const float* u, const float* dt, const float* Bin,
                       const float* Cin, const float* Alog, const float* Ai,
                       const float* Aj, const float* Ak,
                       float* out, void* d_ws, hipStream_t stream) {
    const size_t elems = (size_t)BSZ * SQ * NCH * DQ;
    float4* WQ = (float4*)d_ws;
    float4* WB = WQ + elems;
    dim3 g1(DQ / 128, NCH, BSZ);
    qssm_pass1<NCH><<<g1, 256, 0, stream>>>(u, dt, Bin, Alog, Ai, Aj, Ak, WQ, WB);
    qssm_pass2<NCH><<<(BSZ*SQ*DQ)/16, 16*(NCH/8), 0, stream>>>(WQ, WB);
    dim3 g3(DQ / 128, NCH, BSZ);
    qssm_pass3<NCH><<<g3, 256, 0, stream>>>(u, dt, Bin, Cin, Alog, Ai, Aj, Ak, WB, out);
}

extern "C" void kernel_launch(void* const* d_in, const int* in_sizes, int n_in,
                              void* d_out, int out_size, void* d_ws, size_t ws_size,
                              hipStream_t stream) {
    const float* u    = (const float*)d_in[0];
    const float* dt   = (const float*)d_in[1];
    const float* Bin  = (const float*)d_in[2];
    const float* Cin  = (const float*)d_in[3];
    const float* Alog = (const float*)d_in[4];
    const float* Ai   = (const float*)d_in[5];
    const float* Aj   = (const float*)d_in[6];
    const float* Ak   = (const float*)d_in[7];
    float* out = (float*)d_out;

    // ---- preferred: single-kernel decoupled look-back ----
    const size_t HDR = 16384;   // flags (8*128 ints) + pad + ticket
    const size_t elemsL = (size_t)BSZ * SQ * NCHL * DQ;
    const size_t needL  = HDR + 3 * elemsL * sizeof(float4);
    if (ws_size >= needL) {
        int*    flags  = (int*)d_ws;
        int*    ticket = (int*)((char*)d_ws + 8192);
        float4* WQ = (float4*)((char*)d_ws + HDR);
        float4* WB = WQ + elemsL;
        float4* WH = WB + elemsL;
        hipMemsetAsync(d_ws, 0, HDR, stream);        // zero flags + ticket
        qssm_lookback<<<NCHAIN * NCHL, 512, 0, stream>>>(
            u, dt, Bin, Cin, Alog, Ai, Aj, Ak, flags, ticket, WQ, WB, WH, out);
        return;
    }

    // ---- fallback: proven 3-kernel path ----
    auto ws_need = [](int nch) -> size_t {
        return 2ull * BSZ * SQ * (size_t)nch * DQ * sizeof(float4);
    };
    if (ws_size >= ws_need(256)) {
        launch_all<256>(u, dt, Bin, Cin, Alog, Ai, Aj, Ak, out, d_ws, stream);
    } else if (ws_size >= ws_need(128)) {
        launch_all<128>(u, dt, Bin, Cin, Alog, Ai, Aj, Ak, out, d_ws, stream);
    } else {
        launch_all<64>(u, dt, Bin, Cin, Alog, Ai, Aj, Ak, out, d_ws, stream);
    }
}

// Round 7
// 297.192 us; speedup vs baseline: 4.2744x; 4.2744x over previous
//
#include <hip/hip_runtime.h>
#include <hip/hip_cooperative_groups.h>

namespace cg = cooperative_groups;

#define BSZ   2
#define LSEQ  2048
#define DQ    512
#define SQ    4
#define EPSQ  1e-6f

typedef float nfloat4 __attribute__((ext_vector_type(4)));  // native vec for nontemporal
typedef float nfloat2 __attribute__((ext_vector_type(2)));  // VOP3P packed pair

__device__ __forceinline__ nfloat2 mk2(float x, float y) { nfloat2 v; v.x = x; v.y = y; return v; }

// ---------------- packed quaternion (pairs (r,i),(j,k); v_pk_fma_f32 path) ---
struct PQuat { nfloat2 ri, jk; };

__device__ __forceinline__ PQuat pq_of(const float4 v) {
    PQuat p; p.ri = mk2(v.x, v.y); p.jk = mk2(v.z, v.w); return p;
}
__device__ __forceinline__ float4 f4_of(const PQuat p) {
    return make_float4(p.ri.x, p.ri.y, p.jk.x, p.jk.y);
}

// o = a x b  (8 packed mul/fma vs 16 scalar)
__device__ __forceinline__ PQuat pqmul(const PQuat a, const PQuat b) {
    const float ar = a.ri.x, ai = a.ri.y, aj = a.jk.x, ak = a.jk.y;
    PQuat o;
    o.ri = ar*b.ri + ai*mk2(-b.ri.y,  b.ri.x)
         + aj*mk2(-b.jk.x,  b.jk.y) + ak*mk2(-b.jk.y, -b.jk.x);
    o.jk = ar*b.jk + ai*mk2(-b.jk.y,  b.jk.x)
         + aj*mk2( b.ri.x, -b.ri.y) + ak*mk2( b.ri.y,  b.ri.x);
    return o;
}

// o = a x b + c
__device__ __forceinline__ PQuat pqmuladd(const PQuat a, const PQuat b, const PQuat c) {
    const float ar = a.ri.x, ai = a.ri.y, aj = a.jk.x, ak = a.jk.y;
    PQuat o;
    o.ri = c.ri + ar*b.ri + ai*mk2(-b.ri.y,  b.ri.x)
         + aj*mk2(-b.jk.x,  b.jk.y) + ak*mk2(-b.jk.y, -b.jk.x);
    o.jk = c.jk + ar*b.jk + ai*mk2(-b.jk.y,  b.jk.x)
         + aj*mk2( b.ri.x, -b.ri.y) + ak*mk2( b.ri.y,  b.ri.x);
    return o;
}

// Precomputed per-(d,s) A-quaternion state (hA = 0.5*dt-free part).
struct HA { float r, i; nfloat2 jk; float p2, n2r; };

__device__ __forceinline__ HA load_hA(const float* __restrict__ Alog,
                                      const float* __restrict__ Ai,
                                      const float* __restrict__ Aj,
                                      const float* __restrict__ Ak, int idx) {
    HA h;
    h.r  = -0.5f * __expf(Alog[idx]);
    h.i  =  0.5f * Ai[idx];
    h.jk = mk2(0.5f * Aj[idx], 0.5f * Ak[idx]);
    h.p2 = h.r*h.r + h.i*h.i + h.jk.x*h.jk.x + h.jk.y*h.jk.y;
    h.n2r = -2.0f * h.r;
    return h;
}

// Cayley transition q and injection Bu (packed, strength-reduced).
__device__ __forceinline__ void cayley_pk(const float a, const float aa, const HA& hA,
                                          const PQuat B, const PQuat U,
                                          PQuat& q, PQuat& Bu) {
    const float dd = __builtin_fmaf(aa, hA.p2, __builtin_fmaf(a, hA.n2r, 1.0f + EPSQ));
    const float sv = __builtin_amdgcn_rcpf(dd);
    const float nr = __builtin_fmaf(-aa, hA.p2, 1.0f);   // 1 - |w|^2
    const float as = a * sv;
    const float s2a = as + as;                            // 2*a*s
    q.ri = mk2(nr * sv, s2a * hA.i);
    q.jk = s2a * hA.jk;
    PQuat cd;                                             // conj(den) = (1-wr, w_im)
    cd.ri = mk2(__builtin_fmaf(-a, hA.r, 1.0f), a * hA.i);
    cd.jk = a * hA.jk;
    const PQuat cb = pqmul(cd, B);
    PQuat dB; dB.ri = as * cb.ri; dB.jk = as * cb.jk;
    Bu = pqmul(dB, U);
}

// ---------------- scalar quat (scan path) ------------------------------------
struct Quat { float r, i, j, k; };
__device__ __forceinline__ Quat qmul(const Quat a, const Quat b) {
    Quat o;
    o.r = a.r*b.r - a.i*b.i - a.j*b.j - a.k*b.k;
    o.i = a.r*b.i + a.i*b.r + a.j*b.k - a.k*b.j;
    o.j = a.r*b.j - a.i*b.k + a.j*b.r + a.k*b.i;
    o.k = a.r*b.k + a.i*b.j - a.j*b.i + a.k*b.r;
    return o;
}
__device__ __forceinline__ Quat qmuladd(const Quat a, const Quat b, const Quat c) {
    Quat o;
    o.r = c.r + a.r*b.r - a.i*b.i - a.j*b.j - a.k*b.k;
    o.i = c.i + a.r*b.i + a.i*b.r + a.j*b.k - a.k*b.j;
    o.j = c.j + a.r*b.j - a.i*b.k + a.j*b.r + a.k*b.i;
    o.k = c.k + a.r*b.k + a.i*b.j - a.j*b.i + a.k*b.r;
    return o;
}
__device__ __forceinline__ Quat q_of(const float4 v) { return Quat{v.x, v.y, v.z, v.w}; }
__device__ __forceinline__ float4 f4s_of(const Quat q) { return make_float4(q.r, q.i, q.j, q.k); }

// ---------------- async global->LDS staging helpers --------------------------
typedef unsigned int u32_t;
__device__ __forceinline__ void gl_lds16(const void* g, void* l) {
    __builtin_amdgcn_global_load_lds(
        (const __attribute__((address_space(1))) u32_t*)g,
        (__attribute__((address_space(3))) u32_t*)l, 16, 0, 0);
}
__device__ __forceinline__ void gl_lds4(const void* g, void* l) {
    __builtin_amdgcn_global_load_lds(
        (const __attribute__((address_space(1))) u32_t*)g,
        (__attribute__((address_space(3))) u32_t*)l, 4, 0, 0);
}

// ======================= FUSED cooperative kernel (2x occupancy margin) ======
// 512 blocks x 512 threads, launch_bounds(512,4) => VGPR<=128 (no spill
// pressure; r4 variant compiled at 40). Co-residency needs only 2 blocks/CU;
// LDS 24.5KB allows 6, threads allow 4, VGPR allows >=4 -> >=2x margin on
// every resource (round-5's zero-margin 8-waves/SIMD bet is what hung the
// container). Phases A/C grid-stride 4 tiles with bulk async LDS staging;
// phase B = proven pass2 body on blocks 0..255.
#define NCHF 256
#define CHF  (LSEQ / NCHF)           // 8
#define NTF  (BSZ * NCHF * (DQ/128)) // 2048 tiles

union SMemF {
    struct { float4 uL[CHF][128]; float dtL[CHF][128];
             float4 BL[CHF][SQ];   float4 CL[CHF][SQ]; } ac;
    struct { float4 QL[32][16]; float4 BL2[32][16]; float4 HS[32][16]; } b;
};

__global__ __launch_bounds__(512, 4) void qssm_fused2(
    const float* __restrict__ u, const float* __restrict__ dt,
    const float* __restrict__ Bin, const float* __restrict__ Cin,
    const float* __restrict__ Alog, const float* __restrict__ Ai,
    const float* __restrict__ Aj,   const float* __restrict__ Ak,
    float4* __restrict__ WQ, float4* __restrict__ WB, float* __restrict__ out)
{
    __shared__ SMemF sm;
    cg::grid_group grid = cg::this_grid();
    const int t    = threadIdx.x;
    const int lane = t & 63;
    const int wid  = t >> 6;               // 0..7

    // ---------------- phase A: chunk summaries -> WQ/WB ----------------------
    {
        const int dl = t & 127;
        const int sq = t >> 7;             // s-channel 0..3
        for (int tid = blockIdx.x; tid < NTF; tid += (int)gridDim.x) {
            const int dblk = tid & 3;
            const int c    = (tid >> 2) & (NCHF - 1);
            const int b    =  tid >> 10;
            const int base = b*LSEQ + c*CHF;

            __syncthreads();               // LDS safe to overwrite (next tile)
            const float4* ug  = (const float4*)u + (size_t)base*DQ + dblk*128;
            const float*  dtg = dt + (size_t)base*DQ + dblk*128;
            const float*  Bg  = Bin + (size_t)base*SQ*4;
            {   // wave w stages row w (CHF == 8 waves)
                const int j = wid;
#pragma unroll
                for (int k = 0; k < 2; ++k) {
                    gl_lds16(ug  + (size_t)j*DQ + k*64 + lane, &sm.ac.uL[j][k*64]);
                    gl_lds4 (dtg + (size_t)j*DQ + k*64 + lane, &sm.ac.dtL[j][k*64]);
                }
            }
            if (wid == 0) {
#pragma unroll
                for (int k = 0; k < (CHF*SQ*4)/64; ++k)
                    gl_lds4(Bg + k*64 + lane, ((float*)sm.ac.BL) + k*64);
            }
            const int d = dblk*128 + dl;
            const HA hA = load_hA(Alog, Ai, Aj, Ak, d*SQ + sq);
            __syncthreads();               // drains vmcnt (global_load_lds)

            PQuat Q, Bc;
            {
                const float a = sm.ac.dtL[0][dl];
                cayley_pk(a, a*a, hA, pq_of(sm.ac.BL[0][sq]), pq_of(sm.ac.uL[0][dl]), Q, Bc);
            }
#pragma unroll
            for (int j = 1; j < CHF; ++j) {
                const float a = sm.ac.dtL[j][dl];
                PQuat q, Bu;
                cayley_pk(a, a*a, hA, pq_of(sm.ac.BL[j][sq]), pq_of(sm.ac.uL[j][dl]), q, Bu);
                Bc = pqmuladd(q, Bc, Bu);
                Q  = pqmul(q, Q);
            }
            const size_t idx = ((size_t)(b*SQ + sq)*NCHF + c)*DQ + d;
            WQ[idx] = f4_of(Q);
            WB[idx] = f4_of(Bc);
        }
    }
    grid.sync();

    // ---------------- phase B: hierarchical scan (proven pass2 body) ---------
    if (blockIdx.x < 256) {
        constexpr int GS = 8;
        constexpr int NG = NCHF / GS;      // 32 (512 threads = 32 x 16)
        const int i  = t & 15;
        const int g  = t >> 4;
        const int bs = blockIdx.x >> 5;
        const int d  = (blockIdx.x & 31) * 16 + i;
        const size_t chbase = (size_t)bs * NCHF * DQ + d;

        size_t idx = chbase + (size_t)(g * GS) * DQ;
        Quat Qa = q_of(WQ[idx]);
        Quat Ba = q_of(WB[idx]);
#pragma unroll
        for (int j = 1; j < GS; ++j) {
            idx += DQ;
            const Quat Qc = q_of(WQ[idx]);
            const Quat Bc = q_of(WB[idx]);
            Ba = qmuladd(Qc, Ba, Bc);
            Qa = qmul(Qc, Qa);
        }
        sm.b.QL[g][i]  = f4s_of(Qa);
        sm.b.BL2[g][i] = f4s_of(Ba);
        __syncthreads();

        if (t < 16) {
            Quat h{0.f, 0.f, 0.f, 0.f};
#pragma unroll
            for (int gg = 0; gg < NG; ++gg) {
                sm.b.HS[gg][t] = f4s_of(h);
                h = qmuladd(q_of(sm.b.QL[gg][t]), h, q_of(sm.b.BL2[gg][t]));
            }
        }
        __syncthreads();

        Quat h = q_of(sm.b.HS[g][i]);
        idx = chbase + (size_t)(g * GS) * DQ;
#pragma unroll
        for (int j = 0; j < GS; ++j) {
            const Quat Qc = q_of(WQ[idx]);
            const Quat Bc = q_of(WB[idx]);
            WB[idx] = f4s_of(h);           // h at chunk start, in place
            h = qmuladd(Qc, h, Bc);
            idx += DQ;
        }
    }
    grid.sync();

    // ---------------- phase C: replay with h_start, emit y -------------------
    {
        const int dl   = lane & 15;
        const int sq   = lane >> 4;        // s-channel 0..3
        const int dloc = wid*16 + dl;      // 0..127
        for (int tid = blockIdx.x; tid < NTF; tid += (int)gridDim.x) {
            const int dblk = tid & 3;
            const int c    = (tid >> 2) & (NCHF - 1);
            const int b    =  tid >> 10;
            const int base = b*LSEQ + c*CHF;

            __syncthreads();
            const float4* ug  = (const float4*)u + (size_t)base*DQ + dblk*128;
            const float*  dtg = dt + (size_t)base*DQ + dblk*128;
            const float*  Bg  = Bin + (size_t)base*SQ*4;
            const float*  Cg  = Cin + (size_t)base*SQ*4;
            {
                const int j = wid;
#pragma unroll
                for (int k = 0; k < 2; ++k) {
                    gl_lds16(ug  + (size_t)j*DQ + k*64 + lane, &sm.ac.uL[j][k*64]);
                    gl_lds4 (dtg + (size_t)j*DQ + k*64 + lane, &sm.ac.dtL[j][k*64]);
                }
            }
            if (wid == 0) {
#pragma unroll
                for (int k = 0; k < (CHF*SQ*4)/64; ++k)
                    gl_lds4(Bg + k*64 + lane, ((float*)sm.ac.BL) + k*64);
            } else if (wid == 1) {
#pragma unroll
                for (int k = 0; k < (CHF*SQ*4)/64; ++k)
                    gl_lds4(Cg + k*64 + lane, ((float*)sm.ac.CL) + k*64);
            }
            const int d = dblk*128 + dloc;
            const HA hA = load_hA(Alog, Ai, Aj, Ak, d*SQ + sq);
            PQuat h = pq_of(WB[((size_t)(b*SQ + sq)*NCHF + c)*DQ + d]);   // L2-hot
            nfloat4* outp = (nfloat4*)out + (size_t)base*DQ + d;
            __syncthreads();

#pragma unroll
            for (int j = 0; j < CHF; ++j) {
                const float a = sm.ac.dtL[j][dloc];
                PQuat q, Bu;
                cayley_pk(a, a*a, hA, pq_of(sm.ac.BL[j][sq]), pq_of(sm.ac.uL[j][dloc]), q, Bu);
                h = pqmuladd(q, h, Bu);
                const PQuat y = pqmul(pq_of(sm.ac.CL[j][sq]), h);
                float yr = y.ri.x, yi = y.ri.y, yj = y.jk.x, yk = y.jk.y;
                yr += __shfl_xor(yr, 16); yi += __shfl_xor(yi, 16);
                yj += __shfl_xor(yj, 16); yk += __shfl_xor(yk, 16);
                yr += __shfl_xor(yr, 32); yi += __shfl_xor(yi, 32);
                yj += __shfl_xor(yj, 32); yk += __shfl_xor(yk, 32);
                if (sq == 0) {
                    const nfloat4 yv = {yr, yi, yj, yk};
                    __builtin_nontemporal_store(yv, outp);   // out never re-read
                }
                outp += DQ;
            }
        }
    }
}

// ======================= fallback 3-kernel path (r2, proven 151.7) ===========
template<int NCH>
__global__ __launch_bounds__(256, 6) void qssm_pass1(
    const float* __restrict__ u, const float* __restrict__ dt,
    const float* __restrict__ Bin,
    const float* __restrict__ Alog, const float* __restrict__ Ai,
    const float* __restrict__ Aj,   const float* __restrict__ Ak,
    float4* __restrict__ WQ, float4* __restrict__ WB)
{
    constexpr int CH = LSEQ / NCH;
    __shared__ float4 uL[CH][128];
    __shared__ float  dtL[CH][128];
    __shared__ float4 BL[CH][SQ];

    const int t    = threadIdx.x;
    const int lane = t & 63;
    const int wid  = t >> 6;
    const int dblk = blockIdx.x;
    const int c    = blockIdx.y;
    const int b    = blockIdx.z;
    const int base = b*LSEQ + c*CH;

    const float4* ug  = (const float4*)u + (size_t)base*DQ + dblk*128;
    const float*  dtg = dt + (size_t)base*DQ + dblk*128;
    const float*  Bg  = Bin + (size_t)base*SQ*4;
#pragma unroll
    for (int jj = 0; jj < CH/4; ++jj) {
        const int j = wid*(CH/4) + jj;
#pragma unroll
        for (int k = 0; k < 2; ++k) {
            gl_lds16(ug  + (size_t)j*DQ + k*64 + lane, &uL[j][k*64]);
            gl_lds4 (dtg + (size_t)j*DQ + k*64 + lane, &dtL[j][k*64]);
        }
    }
    if (wid == 0) {
#pragma unroll
        for (int k = 0; k < 2; ++k)
            gl_lds4(Bg + k*64 + lane, ((float*)BL) + k*64);
    }

    const int dl = t & 127;
    const int sh = t >> 7;
    const int s0 = sh * 2;
    const int d  = dblk*128 + dl;

    HA hA0 = load_hA(Alog, Ai, Aj, Ak, d*SQ + s0);
    HA hA1 = load_hA(Alog, Ai, Aj, Ak, d*SQ + s0 + 1);

    __syncthreads();

    PQuat Q[2], Bc[2];
    {
        const float a  = dtL[0][dl];
        const float aa = a * a;
        const PQuat U  = pq_of(uL[0][dl]);
        PQuat q, Bu;
        cayley_pk(a, aa, hA0, pq_of(BL[0][s0]),     U, q, Bu);
        Q[0] = q; Bc[0] = Bu;
        cayley_pk(a, aa, hA1, pq_of(BL[0][s0 + 1]), U, q, Bu);
        Q[1] = q; Bc[1] = Bu;
    }
#pragma unroll
    for (int j = 1; j < CH; ++j) {
        const float a  = dtL[j][dl];
        const float aa = a * a;
        const PQuat U  = pq_of(uL[j][dl]);
        PQuat q, Bu;
        cayley_pk(a, aa, hA0, pq_of(BL[j][s0]),     U, q, Bu);
        Bc[0] = pqmuladd(q, Bc[0], Bu);
        Q[0]  = pqmul(q, Q[0]);
        cayley_pk(a, aa, hA1, pq_of(BL[j][s0 + 1]), U, q, Bu);
        Bc[1] = pqmuladd(q, Bc[1], Bu);
        Q[1]  = pqmul(q, Q[1]);
    }
#pragma unroll
    for (int ss = 0; ss < 2; ++ss) {
        const size_t idx = ((size_t)(b*SQ + s0 + ss)*NCH + c)*DQ + d;
        WQ[idx] = f4_of(Q[ss]);
        WB[idx] = f4_of(Bc[ss]);
    }
}

template<int NCH>
__global__ __launch_bounds__(512) void qssm_pass2(
    const float4* __restrict__ WQ, float4* __restrict__ WB)
{
    constexpr int GS = 8;
    constexpr int NG = NCH / GS;
    __shared__ float4 QL[NG][16];
    __shared__ float4 BL2[NG][16];
    __shared__ float4 HS[NG][16];

    const int t  = threadIdx.x;
    const int i  = t & 15;
    const int g  = t >> 4;
    const int bs = blockIdx.x >> 5;
    const int d  = (blockIdx.x & 31) * 16 + i;
    const size_t chbase = (size_t)bs * NCH * DQ + d;

    size_t idx = chbase + (size_t)(g * GS) * DQ;
    Quat Qa = q_of(WQ[idx]);
    Quat Ba = q_of(WB[idx]);
#pragma unroll
    for (int j = 1; j < GS; ++j) {
        idx += DQ;
        const Quat Qc = q_of(WQ[idx]);
        const Quat Bc = q_of(WB[idx]);
        Ba = qmuladd(Qc, Ba, Bc);
        Qa = qmul(Qc, Qa);
    }
    QL[g][i]  = f4s_of(Qa);
    BL2[g][i] = f4s_of(Ba);
    __syncthreads();

    if (t < 16) {
        Quat h{0.f, 0.f, 0.f, 0.f};
#pragma unroll
        for (int gg = 0; gg < NG; ++gg) {
            HS[gg][t] = f4s_of(h);
            h = qmuladd(q_of(QL[gg][t]), h, q_of(BL2[gg][t]));
        }
    }
    __syncthreads();

    Quat h = q_of(HS[g][i]);
    idx = chbase + (size_t)(g * GS) * DQ;
#pragma unroll
    for (int j = 0; j < GS; ++j) {
        const Quat Qc = q_of(WQ[idx]);
        const Quat Bc = q_of(WB[idx]);
        WB[idx] = f4s_of(h);
        h = qmuladd(Qc, h, Bc);
        idx += DQ;
    }
}

template<int NCH>
__global__ __launch_bounds__(256, 6) void qssm_pass3(
    const float* __restrict__ u, const float* __restrict__ dt,
    const float* __restrict__ Bin, const float* __restrict__ Cin,
    const float* __restrict__ Alog, const float* __restrict__ Ai,
    const float* __restrict__ Aj,   const float* __restrict__ Ak,
    const float4* __restrict__ WB, float* __restrict__ out)
{
    constexpr int CH = LSEQ / NCH;
    __shared__ float4 uL[CH][128];
    __shared__ float  dtL[CH][128];
    __shared__ float4 BL[CH][SQ];
    __shared__ float4 CL[CH][SQ];

    const int t    = threadIdx.x;
    const int lane = t & 63;
    const int wid  = t >> 6;
    const int dblk = blockIdx.x;
    const int c    = blockIdx.y;
    const int b    = blockIdx.z;
    const int base = b*LSEQ + c*CH;

    const float4* ug  = (const float4*)u + (size_t)base*DQ + dblk*128;
    const float*  dtg = dt + (size_t)base*DQ + dblk*128;
    const float*  Bg  = Bin + (size_t)base*SQ*4;
    const float*  Cg  = Cin + (size_t)base*SQ*4;
#pragma unroll
    for (int jj = 0; jj < CH/4; ++jj) {
        const int j = wid*(CH/4) + jj;
#pragma unroll
        for (int k = 0; k < 2; ++k) {
            gl_lds16(ug  + (size_t)j*DQ + k*64 + lane, &uL[j][k*64]);
            gl_lds4 (dtg + (size_t)j*DQ + k*64 + lane, &dtL[j][k*64]);
        }
    }
    if (wid == 0) {
#pragma unroll
        for (int k = 0; k < 2; ++k)
            gl_lds4(Bg + k*64 + lane, ((float*)BL) + k*64);
    } else if (wid == 1) {
#pragma unroll
        for (int k = 0; k < 2; ++k)
            gl_lds4(Cg + k*64 + lane, ((float*)CL) + k*64);
    }

    const int dl   = lane & 31;
    const int sh   = lane >> 5;
    const int s0   = sh * 2;
    const int dloc = wid*32 + dl;
    const int d    = dblk*128 + dloc;

    HA hA0 = load_hA(Alog, Ai, Aj, Ak, d*SQ + s0);
    HA hA1 = load_hA(Alog, Ai, Aj, Ak, d*SQ + s0 + 1);
    PQuat h0 = pq_of(WB[((size_t)(b*SQ + s0    )*NCH + c)*DQ + d]);
    PQuat h1 = pq_of(WB[((size_t)(b*SQ + s0 + 1)*NCH + c)*DQ + d]);

    nfloat4* outp = (nfloat4*)out + (size_t)base*DQ + d;

    __syncthreads();

#pragma unroll
    for (int j = 0; j < CH; ++j) {
        const float a  = dtL[j][dloc];
        const float aa = a * a;
        const PQuat U  = pq_of(uL[j][dloc]);
        PQuat y; y.ri = mk2(0.f, 0.f); y.jk = mk2(0.f, 0.f);
        PQuat q, Bu;
        cayley_pk(a, aa, hA0, pq_of(BL[j][s0]),     U, q, Bu);
        h0 = pqmuladd(q, h0, Bu);
        y  = pqmuladd(pq_of(CL[j][s0]),     h0, y);
        cayley_pk(a, aa, hA1, pq_of(BL[j][s0 + 1]), U, q, Bu);
        h1 = pqmuladd(q, h1, Bu);
        y  = pqmuladd(pq_of(CL[j][s0 + 1]), h1, y);
        float yr = y.ri.x + __shfl_xor(y.ri.x, 32);
        float yi = y.ri.y + __shfl_xor(y.ri.y, 32);
        float yj = y.jk.x + __shfl_xor(y.jk.x, 32);
        float yk = y.jk.y + __shfl_xor(y.jk.y, 32);
        if (sh == 0) {
            const nfloat4 yv = {yr, yi, yj, yk};
            __builtin_nontemporal_store(yv, outp);
        }
        outp += DQ;
    }
}

// ======================= host launch =========================================
template<int NCH>
static void launch_all(const float* u, const float* dt, const float* Bin,
                       const float* Cin, const float* Alog, const float* Ai,
                       const float* Aj, const float* Ak,
                       float* out, void* d_ws, hipStream_t stream) {
    const size_t elems = (size_t)BSZ * SQ * NCH * DQ;
    float4* WQ = (float4*)d_ws;
    float4* WB = WQ + elems;
    dim3 g1(DQ / 128, NCH, BSZ);
    qssm_pass1<NCH><<<g1, 256, 0, stream>>>(u, dt, Bin, Alog, Ai, Aj, Ak, WQ, WB);
    qssm_pass2<NCH><<<(BSZ*SQ*DQ)/16, 16*(NCH/8), 0, stream>>>(WQ, WB);
    dim3 g3(DQ / 128, NCH, BSZ);
    qssm_pass3<NCH><<<g3, 256, 0, stream>>>(u, dt, Bin, Cin, Alog, Ai, Aj, Ak, WB, out);
}

extern "C" void kernel_launch(void* const* d_in, const int* in_sizes, int n_in,
                              void* d_out, int out_size, void* d_ws, size_t ws_size,
                              hipStream_t stream) {
    const float* u    = (const float*)d_in[0];
    const float* dt   = (const float*)d_in[1];
    const float* Bin  = (const float*)d_in[2];
    const float* Cin  = (const float*)d_in[3];
    const float* Alog = (const float*)d_in[4];
    const float* Ai   = (const float*)d_in[5];
    const float* Aj   = (const float*)d_in[6];
    const float* Ak   = (const float*)d_in[7];
    float* out = (float*)d_out;

    // ---- preferred: single cooperative fused kernel, 2x co-residency margin --
    const size_t elemsF = (size_t)BSZ * SQ * NCHF * DQ;
    if (ws_size >= 2 * elemsF * sizeof(float4)) {
        float4* WQ = (float4*)d_ws;
        float4* WB = WQ + elemsF;
        void* kargs[] = {(void*)&u, (void*)&dt, (void*)&Bin, (void*)&Cin,
                         (void*)&Alog, (void*)&Ai, (void*)&Aj, (void*)&Ak,
                         (void*)&WQ, (void*)&WB, (void*)&out};
        hipError_t e = hipLaunchCooperativeKernel(
            reinterpret_cast<void*>(qssm_fused2),
            dim3(512), dim3(512), kargs, 0, stream);
        if (e == hipSuccess) return;
        (void)hipGetLastError();   // clear sticky error, fall back
    }

    // ---- fallback: proven 3-kernel path ----
    auto ws_need = [](int nch) -> size_t {
        return 2ull * BSZ * SQ * (size_t)nch * DQ * sizeof(float4);
    };
    if (ws_size >= ws_need(256)) {
        launch_all<256>(u, dt, Bin, Cin, Alog, Ai, Aj, Ak, out, d_ws, stream);
    } else if (ws_size >= ws_need(128)) {
        launch_all<128>(u, dt, Bin, Cin, Alog, Ai, Aj, Ak, out, d_ws, stream);
    } else {
        launch_all<64>(u, dt, Bin, Cin, Alog, Ai, Aj, Ak, out, d_ws, stream);
    }
}

// Round 8
// 145.643 us; speedup vs baseline: 8.7223x; 2.0406x over previous
//
#include <hip/hip_runtime.h>

#define BSZ   2
#define LSEQ  2048
#define DQ    512
#define SQ    4
#define EPSQ  1e-6f

typedef float nfloat4 __attribute__((ext_vector_type(4)));  // native vec for nontemporal
typedef float nfloat2 __attribute__((ext_vector_type(2)));  // VOP3P packed pair

__device__ __forceinline__ nfloat2 mk2(float x, float y) { nfloat2 v; v.x = x; v.y = y; return v; }

// ---------------- packed quaternion (pairs (r,i),(j,k); v_pk_fma_f32 path) ---
struct PQuat { nfloat2 ri, jk; };

__device__ __forceinline__ PQuat pq_of(const float4 v) {
    PQuat p; p.ri = mk2(v.x, v.y); p.jk = mk2(v.z, v.w); return p;
}
__device__ __forceinline__ float4 f4_of(const PQuat p) {
    return make_float4(p.ri.x, p.ri.y, p.jk.x, p.jk.y);
}

// o = a x b  (8 packed mul/fma vs 16 scalar)
__device__ __forceinline__ PQuat pqmul(const PQuat a, const PQuat b) {
    const float ar = a.ri.x, ai = a.ri.y, aj = a.jk.x, ak = a.jk.y;
    PQuat o;
    o.ri = ar*b.ri + ai*mk2(-b.ri.y,  b.ri.x)
         + aj*mk2(-b.jk.x,  b.jk.y) + ak*mk2(-b.jk.y, -b.jk.x);
    o.jk = ar*b.jk + ai*mk2(-b.jk.y,  b.jk.x)
         + aj*mk2( b.ri.x, -b.ri.y) + ak*mk2( b.ri.y,  b.ri.x);
    return o;
}

// o = a x b + c
__device__ __forceinline__ PQuat pqmuladd(const PQuat a, const PQuat b, const PQuat c) {
    const float ar = a.ri.x, ai = a.ri.y, aj = a.jk.x, ak = a.jk.y;
    PQuat o;
    o.ri = c.ri + ar*b.ri + ai*mk2(-b.ri.y,  b.ri.x)
         + aj*mk2(-b.jk.x,  b.jk.y) + ak*mk2(-b.jk.y, -b.jk.x);
    o.jk = c.jk + ar*b.jk + ai*mk2(-b.jk.y,  b.jk.x)
         + aj*mk2( b.ri.x, -b.ri.y) + ak*mk2( b.ri.y,  b.ri.x);
    return o;
}

// Cayley transition q and injection Bu (packed).
// q  = s*(1-|w|^2, 2wi, 2wj, 2wk), w = a*hA, s = 1/((1-wr)^2+|w_im|^2+eps)
// Bu = (a*s) * (conj(den) x B) x u, conj(den) = (1-wr, wi, wj, wk)
__device__ __forceinline__ void cayley_pk(const float a, const PQuat hA,
                                          const PQuat B, const PQuat U,
                                          PQuat& q, PQuat& Bu) {
    const nfloat2 w_ri = a * hA.ri;
    const nfloat2 w_jk = a * hA.jk;
    const float wr = w_ri.x, wi = w_ri.y;
    const float m  = wi*wi + w_jk.x*w_jk.x + w_jk.y*w_jk.y;
    const float e  = 1.0f - wr;
    const float dd = e*e + m + EPSQ;
    const float sv = __builtin_amdgcn_rcpf(dd);
    const float s2 = sv + sv;
    q.ri = mk2(sv * (1.0f - (wr*wr + m)), s2 * wi);
    q.jk = s2 * w_jk;
    PQuat cd; cd.ri = mk2(e, wi); cd.jk = w_jk;
    const PQuat cb = pqmul(cd, B);
    const float as = a * sv;
    PQuat dB; dB.ri = as * cb.ri; dB.jk = as * cb.jk;
    Bu = pqmul(dB, U);
}

__device__ __forceinline__ PQuat load_hA_pk(const float* __restrict__ Alog,
                                            const float* __restrict__ Ai,
                                            const float* __restrict__ Aj,
                                            const float* __restrict__ Ak, int idx) {
    PQuat p;
    p.ri = mk2(-0.5f * __expf(Alog[idx]), 0.5f * Ai[idx]);
    p.jk = mk2( 0.5f * Aj[idx],           0.5f * Ak[idx]);
    return p;
}

// ---------------- scalar quat (pass2 only — known-good path) ----------------
struct Quat { float r, i, j, k; };
__device__ __forceinline__ Quat qmul(const Quat a, const Quat b) {
    Quat o;
    o.r = a.r*b.r - a.i*b.i - a.j*b.j - a.k*b.k;
    o.i = a.r*b.i + a.i*b.r + a.j*b.k - a.k*b.j;
    o.j = a.r*b.j - a.i*b.k + a.j*b.r + a.k*b.i;
    o.k = a.r*b.k + a.i*b.j - a.j*b.i + a.k*b.r;
    return o;
}
__device__ __forceinline__ Quat qmuladd(const Quat a, const Quat b, const Quat c) {
    Quat o;
    o.r = c.r + a.r*b.r - a.i*b.i - a.j*b.j - a.k*b.k;
    o.i = c.i + a.r*b.i + a.i*b.r + a.j*b.k - a.k*b.j;
    o.j = c.j + a.r*b.j - a.i*b.k + a.j*b.r + a.k*b.i;
    o.k = c.k + a.r*b.k + a.i*b.j - a.j*b.i + a.k*b.r;
    return o;
}
__device__ __forceinline__ Quat q_of(const float4 v) { return Quat{v.x, v.y, v.z, v.w}; }
__device__ __forceinline__ float4 f4s_of(const Quat q) { return make_float4(q.r, q.i, q.j, q.k); }

// ---------------- pass 1: chunk summaries, 2 s-channels per thread -----------
// grid: (DQ/256, NCH, BSZ*2), block 256. z encodes (b, s-half).
// (256,6): ~85 VGPR cap, 6 waves/SIMD. W layout: [b][s][c][d] float4.
// NCH=128 (CH=16): same total step count as NCH=256, half the W traffic.
template<int NCH>
__global__ __launch_bounds__(256, 6) void qssm_pass1(
    const float* __restrict__ u, const float* __restrict__ dt,
    const float* __restrict__ Bin,
    const float* __restrict__ Alog, const float* __restrict__ Ai,
    const float* __restrict__ Aj,   const float* __restrict__ Ak,
    float4* __restrict__ WQ, float4* __restrict__ WB)
{
    constexpr int CH = LSEQ / NCH;
    const int d  = blockIdx.x * 256 + threadIdx.x;
    const int c  = blockIdx.y;
    const int b  = blockIdx.z >> 1;
    const int s0 = (blockIdx.z & 1) * 2;   // this block handles s0, s0+1
    const int t0 = c * CH;

    PQuat hA[2];
    hA[0] = load_hA_pk(Alog, Ai, Aj, Ak, d*SQ + s0);
    hA[1] = load_hA_pk(Alog, Ai, Aj, Ak, d*SQ + s0 + 1);

    const int base = (b*LSEQ + t0);
    const float*  dtp = dt + (size_t)base*DQ + d;
    const float4* up  = (const float4*)u   + (size_t)base*DQ + d;
    const float4* Bp  = (const float4*)Bin + (size_t)base*SQ + s0;

    PQuat Q[2], Bc[2];
    // peel j = 0 (summary starts at identity)
    {
        const float a  = *dtp;
        const PQuat U  = pq_of(*up);
#pragma unroll
        for (int ss = 0; ss < 2; ++ss) {
            PQuat q, Bu;
            cayley_pk(a, hA[ss], pq_of(Bp[ss]), U, q, Bu);
            Q[ss] = q; Bc[ss] = Bu;
        }
        dtp += DQ; up += DQ; Bp += SQ;
    }
#pragma unroll 2
    for (int j = 1; j < CH; ++j) {
        const float a  = *dtp;
        const PQuat U  = pq_of(*up);
#pragma unroll
        for (int ss = 0; ss < 2; ++ss) {
            PQuat q, Bu;
            cayley_pk(a, hA[ss], pq_of(Bp[ss]), U, q, Bu);
            Bc[ss] = pqmuladd(q, Bc[ss], Bu);   // B' = q x B + Bu
            Q[ss]  = pqmul(q, Q[ss]);           // Q' = q x Q
        }
        dtp += DQ; up += DQ; Bp += SQ;
    }
#pragma unroll
    for (int ss = 0; ss < 2; ++ss) {
        const size_t idx = ((size_t)(b*SQ + s0 + ss)*NCH + c)*DQ + d;
        WQ[idx] = f4_of(Q[ss]);
        WB[idx] = f4_of(Bc[ss]);
    }
}

// ---------------- pass 2: hierarchical scan, coalesced over d ----------------
// Block = 16 consecutive d-channels of one (b,s); thread (i = t&15, g = t>>4)
// owns superchunk g (GS=8 chunks). Step-1 chunk summaries are REGISTER-CACHED
// (qv/bv[8] = 64 VGPR) so step 3 replays without re-reading WQ/WB — removes a
// full WQ+WB re-read from HBM/L2. Overwrites WB[c] with h at chunk c's start.
template<int NCH>
__global__ __launch_bounds__(512) void qssm_pass2(
    const float4* __restrict__ WQ, float4* __restrict__ WB)
{
    constexpr int GS = 8;           // chunks per superchunk
    constexpr int NG = NCH / GS;    // superchunks per channel
    __shared__ float4 QL[NG][16];
    __shared__ float4 BL[NG][16];
    __shared__ float4 HS[NG][16];

    const int t  = threadIdx.x;
    const int i  = t & 15;          // local channel (d offset)
    const int g  = t >> 4;          // superchunk
    const int bs = blockIdx.x >> 5;             // (b*SQ+s), 0..7
    const int d  = (blockIdx.x & 31) * 16 + i;  // 0..511
    const size_t chbase = (size_t)bs * NCH * DQ + d;

    // step 1: load + compose chunks c = g*GS .. g*GS+GS-1 (earlier-first),
    // caching the summaries in registers for step 3.
    float4 qv[GS], bv[GS];
    size_t idx = chbase + (size_t)(g * GS) * DQ;
#pragma unroll
    for (int j = 0; j < GS; ++j) {
        qv[j] = WQ[idx];
        bv[j] = WB[idx];
        idx += DQ;
    }
    Quat Qa = q_of(qv[0]);
    Quat Ba = q_of(bv[0]);
#pragma unroll
    for (int j = 1; j < GS; ++j) {
        const Quat Qc = q_of(qv[j]);
        const Quat Bc = q_of(bv[j]);
        Ba = qmuladd(Qc, Ba, Bc);
        Qa = qmul(Qc, Qa);
    }
    QL[g][i] = f4s_of(Qa);
    BL[g][i] = f4s_of(Ba);
    __syncthreads();

    // step 2: 16 threads scan superchunk summaries (h0 = 0)
    if (t < 16) {
        Quat h{0.f, 0.f, 0.f, 0.f};
#pragma unroll
        for (int gg = 0; gg < NG; ++gg) {
            HS[gg][t] = f4s_of(h);
            h = qmuladd(q_of(QL[gg][t]), h, q_of(BL[gg][t]));
        }
    }
    __syncthreads();

    // step 3: replay own superchunk from registers, store h at chunk starts
    Quat h = q_of(HS[g][i]);
    idx = chbase + (size_t)(g * GS) * DQ;
#pragma unroll
    for (int j = 0; j < GS; ++j) {
        WB[idx] = f4s_of(h);
        h = qmuladd(q_of(qv[j]), h, q_of(bv[j]));
        idx += DQ;
    }
}

// ---------------- pass 3: replay with correct h_start, emit output -----------
// grid: (DQ/128, NCH, BSZ), block 256 = 4 waves. Each wave: 32 d x 2 s-halves
// (lane = 32*sh + dl). Partial y reduced across halves via shfl_xor(32);
// lanes sh==0 store (contiguous addresses).
template<int NCH>
__global__ __launch_bounds__(256, 6) void qssm_pass3(
    const float* __restrict__ u, const float* __restrict__ dt,
    const float* __restrict__ Bin, const float* __restrict__ Cin,
    const float* __restrict__ Alog, const float* __restrict__ Ai,
    const float* __restrict__ Aj,   const float* __restrict__ Ak,
    const float4* __restrict__ WB, float* __restrict__ out)
{
    constexpr int CH = LSEQ / NCH;
    const int t    = threadIdx.x;
    const int lane = t & 63;
    const int wv   = t >> 6;
    const int dl   = lane & 31;
    const int sh   = lane >> 5;            // s-half: 0 or 1
    const int s0   = sh * 2;
    const int d = blockIdx.x * 128 + wv * 32 + dl;
    const int c = blockIdx.y;
    const int b = blockIdx.z;
    const int t0 = c * CH;

    PQuat hA[2];
    PQuat h[2];
#pragma unroll
    for (int ss = 0; ss < 2; ++ss) {
        hA[ss] = load_hA_pk(Alog, Ai, Aj, Ak, d*SQ + s0 + ss);
        h[ss] = pq_of(WB[((size_t)(b*SQ + s0 + ss)*NCH + c)*DQ + d]);
    }
    const int base = (b*LSEQ + t0);
    const float*  dtp  = dt + (size_t)base*DQ + d;
    const float4* up   = (const float4*)u   + (size_t)base*DQ + d;
    const float4* Bp   = (const float4*)Bin + (size_t)base*SQ + s0;
    const float4* Cp   = (const float4*)Cin + (size_t)base*SQ + s0;
    nfloat4*      outp = (nfloat4*)out + (size_t)base*DQ + d;

#pragma unroll 2
    for (int j = 0; j < CH; ++j) {
        const float a  = *dtp;
        const PQuat U  = pq_of(*up);
        PQuat y; y.ri = mk2(0.f, 0.f); y.jk = mk2(0.f, 0.f);
#pragma unroll
        for (int ss = 0; ss < 2; ++ss) {
            const PQuat Cq = pq_of(Cp[ss]);
            PQuat q, Bu;
            cayley_pk(a, hA[ss], pq_of(Bp[ss]), U, q, Bu);
            h[ss] = pqmuladd(q, h[ss], Bu);
            y = pqmuladd(Cq, h[ss], y);
        }
        // reduce partial y across the two s-halves (lanes l and l^32)
        float yr = y.ri.x + __shfl_xor(y.ri.x, 32);
        float yi = y.ri.y + __shfl_xor(y.ri.y, 32);
        float yj = y.jk.x + __shfl_xor(y.jk.x, 32);
        float yk = y.jk.y + __shfl_xor(y.jk.y, 32);
        if (sh == 0) {
            const nfloat4 yv = {yr, yi, yj, yk};
            __builtin_nontemporal_store(yv, outp);  // out never re-read
        }
        dtp += DQ; up += DQ; Bp += SQ; Cp += SQ; outp += DQ;
    }
}

template<int NCH>
static void launch_all(const float* u, const float* dt, const float* Bin,
                       const float* Cin, const float* Alog, const float* Ai,
                       const float* Aj, const float* Ak,
                       float* out, void* d_ws, hipStream_t stream) {
    const size_t elems = (size_t)BSZ * SQ * NCH * DQ;
    float4* WQ = (float4*)d_ws;
    float4* WB = WQ + elems;
    dim3 g1(DQ / 256, NCH, BSZ * 2);
    qssm_pass1<NCH><<<g1, 256, 0, stream>>>(u, dt, Bin, Alog, Ai, Aj, Ak, WQ, WB);
    qssm_pass2<NCH><<<(BSZ*SQ*DQ)/16, 16*(NCH/8), 0, stream>>>(WQ, WB);
    dim3 g3(DQ / 128, NCH, BSZ);
    qssm_pass3<NCH><<<g3, 256, 0, stream>>>(u, dt, Bin, Cin, Alog, Ai, Aj, Ak, WB, out);
}

extern "C" void kernel_launch(void* const* d_in, const int* in_sizes, int n_in,
                              void* d_out, int out_size, void* d_ws, size_t ws_size,
                              hipStream_t stream) {
    const float* u    = (const float*)d_in[0];
    const float* dt   = (const float*)d_in[1];
    const float* Bin  = (const float*)d_in[2];
    const float* Cin  = (const float*)d_in[3];
    const float* Alog = (const float*)d_in[4];
    const float* Ai   = (const float*)d_in[5];
    const float* Aj   = (const float*)d_in[6];
    const float* Ak   = (const float*)d_in[7];
    float* out = (float*)d_out;

    auto ws_need = [](int nch) -> size_t {
        return 2ull * BSZ * SQ * (size_t)nch * DQ * sizeof(float4);
    };
    // NCH=128: half the W footprint/traffic of 256, same per-thread work in
    // pass1/pass3 (CH=16). Grid still >=1024 blocks for the sweep kernels.
    if (ws_size >= ws_need(128)) {
        launch_all<128>(u, dt, Bin, Cin, Alog, Ai, Aj, Ak, out, d_ws, stream);
    } else {
        launch_all<64>(u, dt, Bin, Cin, Alog, Ai, Aj, Ak, out, d_ws, stream);
    }
}